// Round 12
// baseline (6950.660 us; speedup 1.0000x reference)
//
#include <hip/hip_runtime.h>

// Recurrent spiking LIF network: T=64, B=32, NE=4096, NI=1024, N=5120.
// fp64 accumulation => spike-identical to fp64 numpy ref (rounds 2-11: 0.0).
//
// Round-12: SPIKES ARE BITS. Pack 32 batch-spikes per source neuron into
// mask[k] (u32). mv has NO LDS and NO spike values: per (k, j) a wave-
// uniform scalar branch (s_bitcmp+s_cbranch) guards two v_add_f64.
//  - kills LDS pipe (32us/step), spike cvts (10.7us), ~75% of fp64 adds.
//  - skipped terms are exact zeros -> bit-identical fp64 trajectory.
//  - grid (40,32) x 256thr = 1280 blocks = exactly 5/CU (no LDS -> no
//    staging duplication, round-11's FETCH blowup cause is gone).
//  - weights + masks 1-quad-ahead register prefetch.

#define NE 4096
#define NI 1024
#define NN 5120
#define HN 2560      // NN/2
#define BB 32

// ---------------- spike pack kernel ----------------
// out_t[b][n] (0.0/1.0 floats just written by upd) -> mask[n] bit b.
__global__ __launch_bounds__(256) void pack_kernel(
    const float* __restrict__ out_t, unsigned* __restrict__ mask)
{
    const int n = blockIdx.x * 256 + threadIdx.x;   // 5120 = 20*256 exact
    unsigned m = 0;
#pragma unroll
    for (int b = 0; b < BB; ++b)
        m |= (out_t[(size_t)b * NN + n] > 0.5f ? 1u : 0u) << b;
    mask[n] = m;
}

// ---------------- sparse matvec partial kernel ----------------
// grid: (HN/64, G), block 256 = 64 tn x 4 j-groups of 8 batches.
// Thread owns neurons {nA = bx*64+tn, nA+2560} x batches [jg*8, jg*8+8).
template <int KR>
__global__ __launch_bounds__(256) void mv_kernel(
    const float* __restrict__ W_ee, const float* __restrict__ W_ei,
    const float* __restrict__ W_ie, const float* __restrict__ W_ii,
    const unsigned* __restrict__ mask,   // [NN] spike bitmasks (bit b = batch b)
    double* __restrict__ partial)        // [G][BB][NN]
{
    const int t  = threadIdx.x;
    const int tn = t & 63;
    const int jh = __builtin_amdgcn_readfirstlane((t >> 6) << 3);  // 0,8,16,24
    const int nA = blockIdx.x * 64 + tn;       // 0..2559 (< NE: E-target)
    const int nB = nA + HN;                    // 2560..5119 (mixed)
    const int kb = blockIdx.y * KR;

    double accA[8], accB[8];
#pragma unroll
    for (int j = 0; j < 8; ++j) { accA[j] = 0.0; accB[j] = 0.0; }

    const float* __restrict__ rEA = W_ee + (size_t)nA * NE;   // nA < NE
    const float* __restrict__ rIA = W_ie + (size_t)nA * NI;
    const float* __restrict__ rEB = (nB < NE) ? (W_ee + (size_t)nB * NE)
                                              : (W_ei + (size_t)(nB - NE) * NE);
    const float* __restrict__ rIB = (nB < NE) ? (W_ie + (size_t)nB * NI)
                                              : (W_ii + (size_t)(nB - NE) * NI);

    int aEnd = NE - kb;                        // E/I source boundary
    if (aEnd < 0) aEnd = 0;
    if (aEnd > KR) aEnd = KR;                  // always a multiple of 4

    // one segment: weight rows pA/pB, masks pM, length len (multiple of 4)
    auto run = [&](const float* __restrict__ pA, const float* __restrict__ pB,
                   const unsigned* __restrict__ pM, int len) {
        if (len <= 0) return;
        float4 wa = *reinterpret_cast<const float4*>(pA);
        float4 wb = *reinterpret_cast<const float4*>(pB);
        uint4  mq = *reinterpret_cast<const uint4*>(pM);
        for (int kk = 0; kk < len; kk += 4) {
            const float4 cwa = wa, cwb = wb;
            const uint4  cmq = mq;
            if (kk + 4 < len) {                // uniform branch: prefetch
                wa = *reinterpret_cast<const float4*>(pA + kk + 4);
                wb = *reinterpret_cast<const float4*>(pB + kk + 4);
                mq = *reinterpret_cast<const uint4*>(pM + kk + 4);
            }
            // wave-uniform masks in SGPRs; this wave's 8 batches
            const unsigned m0 = (__builtin_amdgcn_readfirstlane(cmq.x) >> jh) & 0xFFu;
            const unsigned m1 = (__builtin_amdgcn_readfirstlane(cmq.y) >> jh) & 0xFFu;
            const unsigned m2 = (__builtin_amdgcn_readfirstlane(cmq.z) >> jh) & 0xFFu;
            const unsigned m3 = (__builtin_amdgcn_readfirstlane(cmq.w) >> jh) & 0xFFu;
            if ((m0 | m1 | m2 | m3) == 0u) continue;   // scalar skip (t=0 fast)

            const double wa0 = (double)cwa.x, wa1 = (double)cwa.y,
                         wa2 = (double)cwa.z, wa3 = (double)cwa.w;
            const double wb0 = (double)cwb.x, wb1 = (double)cwb.y,
                         wb2 = (double)cwb.z, wb3 = (double)cwb.w;
#pragma unroll
            for (int j = 0; j < 8; ++j) {
                if (m0 & (1u << j)) { accA[j] += wa0; accB[j] += wb0; }
                if (m1 & (1u << j)) { accA[j] += wa1; accB[j] += wb1; }
                if (m2 & (1u << j)) { accA[j] += wa2; accB[j] += wb2; }
                if (m3 & (1u << j)) { accA[j] += wa3; accB[j] += wb3; }
            }
        }
    };

    // excitatory sources [kb, kb+aEnd), then inhibitory [kb+aEnd, kb+KR)
    run(rEA + kb, rEB + kb, mask + kb, aEnd);
    run(rIA + (kb + aEnd - NE), rIB + (kb + aEnd - NE), mask + kb + aEnd,
        KR - aEnd);

#pragma unroll
    for (int j = 0; j < 8; ++j) {
        const size_t base = ((size_t)blockIdx.y * BB + jh + j) * NN;
        partial[base + nA] = accA[j];
        partial[base + nB] = accB[j];
    }
}

// ---------------- LIF update kernel ----------------
template <int G>
__global__ __launch_bounds__(256) void upd_kernel(
    const float* __restrict__ ext_exc,   // [T][BB][NE]
    const float* __restrict__ ext_inh,   // [T][BB][NI]
    const double* __restrict__ partial,  // [G][BB][NN]
    double* __restrict__ v,              // [BB][NN]
    float* __restrict__ out,             // [T][BB][NN]
    int t)
{
    const int idx = blockIdx.x * 256 + threadIdx.x;   // < BB*NN
    const int b = idx / NN;
    const int n = idx - b * NN;

    const float ext = (n < NE)
        ? ext_exc[((size_t)t * BB + b) * NE + n]
        : ext_inh[((size_t)t * BB + b) * NI + (n - NE)];

    double acc = (double)ext;
#pragma unroll
    for (int g = 0; g < G; ++g)
        acc += partial[((size_t)g * BB + b) * NN + n];

    const double vv = v[idx] * 0.9 + acc;
    const double sp = (vv > 1.0) ? 1.0 : 0.0;
    out[(size_t)t * BB * NN + idx] = (float)sp;
    v[idx] = vv * (1.0 - sp);
}

extern "C" void kernel_launch(void* const* d_in, const int* in_sizes, int n_in,
                              void* d_out, int out_size, void* d_ws, size_t ws_size,
                              hipStream_t stream) {
    const float* ext_exc = (const float*)d_in[0];
    const float* ext_inh = (const float*)d_in[1];
    const float* W_ee = (const float*)d_in[2];
    const float* W_ei = (const float*)d_in[3];
    const float* W_ie = (const float*)d_in[4];
    const float* W_ii = (const float*)d_in[5];
    float* out = (float*)d_out;

    const int T = in_sizes[0] / (BB * NE);   // 64

    const size_t SN = (size_t)BB * NN;       // 163840
    double* v = (double*)d_ws;               // [BB][NN] fp64
    unsigned* mask = (unsigned*)(v + SN);    // [NN] u32
    double* partial = (double*)((char*)d_ws + SN * 8 + NN * 4);  // [G][BB][NN]
    const size_t stateBytes = SN * 8 + NN * 4;   // v + mask, ~1.33 MB

    // largest k-split G whose fp64 partial fits (rounds 2-11 proved 44MB fits)
    int G = 32;
    while (G > 8 && stateBytes + (size_t)G * SN * sizeof(double) > ws_size) G >>= 1;

    hipMemsetAsync(d_ws, 0, stateBytes, stream);   // v = 0, mask = 0

    for (int t = 0; t < T; ++t) {
        switch (G) {
            case 32:
                mv_kernel<160> <<<dim3(HN/64, 32), 256, 0, stream>>>(W_ee, W_ei, W_ie, W_ii, mask, partial);
                upd_kernel<32><<<(int)(SN/256), 256, 0, stream>>>(ext_exc, ext_inh, partial, v, out, t);
                break;
            case 16:
                mv_kernel<320> <<<dim3(HN/64, 16), 256, 0, stream>>>(W_ee, W_ei, W_ie, W_ii, mask, partial);
                upd_kernel<16><<<(int)(SN/256), 256, 0, stream>>>(ext_exc, ext_inh, partial, v, out, t);
                break;
            default:
                mv_kernel<640> <<<dim3(HN/64, 8), 256, 0, stream>>>(W_ee, W_ei, W_ie, W_ii, mask, partial);
                upd_kernel<8> <<<(int)(SN/256), 256, 0, stream>>>(ext_exc, ext_inh, partial, v, out, t);
                break;
        }
        pack_kernel<<<NN/256, 256, 0, stream>>>(out + (size_t)t * SN, mask);
    }
}

// Round 13
// 5662.942 us; speedup vs baseline: 1.2274x; 1.2274x over previous
//
#include <hip/hip_runtime.h>

// Recurrent spiking LIF network: T=64, B=32, NE=4096, NI=1024, N=5120.
// fp64 accumulation => spike-identical to fp64 numpy ref (rounds 2-12: 0.0).
//
// Round-13: weights in LDS (global_load_lds, fetched ONCE per tile),
// spikes as bitmask in SGPRs, dense fma with bit->fp64 cvt.
//  - r12 lesson: no-LDS weight streams are re-fetched per j-wave (FETCH
//    172MB). LDS staging shares them across all 4 j-group waves.
//  - r9 lesson: spike LDS was the pipe bound (16 b128/quad). Now 2.
//  - k-major LDS tile [q][row]: lanes read consecutive 16B -> conflict-free.
//  - chunk=64 k: NE%64==0 -> chunk is purely E-source or I-source.

#define NE 4096
#define NI 1024
#define NN 5120
#define HN 2560
#define BB 32
#define CHUNK 64

typedef unsigned int u32;

__device__ __forceinline__ void load_lds16(const float* g, float* l) {
    __builtin_amdgcn_global_load_lds(
        (const __attribute__((address_space(1))) u32*)g,
        (__attribute__((address_space(3))) u32*)l, 16, 0, 0);
}

// ---------------- spike pack kernel ----------------
__global__ __launch_bounds__(256) void pack_kernel(
    const float* __restrict__ out_t, u32* __restrict__ mask)
{
    const int n = blockIdx.x * 256 + threadIdx.x;   // NN = 20*256 exact
    u32 m = 0;
#pragma unroll
    for (int b = 0; b < BB; ++b)
        m |= (out_t[(size_t)b * NN + n] > 0.5f ? 1u : 0u) << b;
    mask[n] = m;
}

// ---------------- matvec partial kernel ----------------
// grid: (HN/64, G), block 256 = 64 n-lanes x 4 j-groups(8 batches).
// Thread owns neurons {nA = bx*64+lane, nA+2560} x batches [jh, jh+8).
template <int KR>
__global__ __launch_bounds__(256) void mv_kernel(
    const float* __restrict__ W_ee, const float* __restrict__ W_ei,
    const float* __restrict__ W_ie, const float* __restrict__ W_ii,
    const u32* __restrict__ mask,    // [NN] spike bitmasks (bit b = batch b)
    double* __restrict__ partial)    // [G][BB][NN]
{
    __shared__ __align__(16) float tile[16 * 128 * 4];   // [q][row][4], 32 KB
    const int t    = threadIdx.x;
    const int lane = t & 63;
    const int wv   = t >> 6;                 // wave id = j-group
    const int jh   = wv << 3;                // 0,8,16,24
    const int nA   = blockIdx.x * 64 + lane; // < HN, always E-target
    const int kb0  = blockIdx.y * KR;

    // block-uniform row bases for the two n-halves, per source segment
    const int n0 = blockIdx.x * 64;          // half 0: < NE
    const int n1 = n0 + HN;                  // half 1: may be >= NE
    const bool h1E = (n1 < NE);
    const float* e0 = W_ee + (size_t)n0 * NE;
    const float* e1 = h1E ? (W_ee + (size_t)n1 * NE) : (W_ei + (size_t)(n1 - NE) * NE);
    const float* i0 = W_ie + (size_t)n0 * NI;
    const float* i1 = h1E ? (W_ie + (size_t)n1 * NI) : (W_ii + (size_t)(n1 - NE) * NI);

    double accA[8], accB[8];
#pragma unroll
    for (int j = 0; j < 8; ++j) { accA[j] = 0.0; accB[j] = 0.0; }

    for (int ch = 0; ch < KR / CHUNK; ++ch) {
        const int kb = kb0 + ch * CHUNK;
        const bool eseg = (kb < NE);         // chunk never straddles (NE%64==0)
        const int kloc = eseg ? kb : kb - NE;
        const size_t kdim = eseg ? NE : NI;
        const float* b0 = eseg ? e0 : i0;
        const float* b1 = eseg ? e1 : i1;

        if (ch) __syncthreads();             // protect tile overwrite
        // stage 128 rows x 64 k fp32: 32 slots of (64 lanes x 16B).
        // slot = wv*8+c: q = slot>>1 (k-quad), h = slot&1 (n-half);
        // lane l stages row l of half h, quad q. LDS dest = uniform
        // base + lane*16 (required global_load_lds pattern).
#pragma unroll
        for (int c = 0; c < 8; ++c) {
            const int slot = wv * 8 + c;
            const int q = slot >> 1;
            const float* base = (slot & 1) ? b1 : b0;
            const float* gsrc = base + (size_t)lane * kdim + (kloc + q * 4);
            load_lds16(gsrc, &tile[slot * 256]);
        }
        __syncthreads();                     // drains vmcnt -> tile valid

        // compute 16 k-quads from LDS
#pragma unroll 4
        for (int q = 0; q < 16; ++q) {
            const float4 wa = *reinterpret_cast<const float4*>(&tile[(q * 128 + lane) * 4]);
            const float4 wb = *reinterpret_cast<const float4*>(&tile[(q * 128 + 64 + lane) * 4]);
            const uint4 mq = *reinterpret_cast<const uint4*>(&mask[kb + q * 4]);
            const u32 m0 = ((u32)__builtin_amdgcn_readfirstlane(mq.x)) >> jh;
            const u32 m1 = ((u32)__builtin_amdgcn_readfirstlane(mq.y)) >> jh;
            const u32 m2 = ((u32)__builtin_amdgcn_readfirstlane(mq.z)) >> jh;
            const u32 m3 = ((u32)__builtin_amdgcn_readfirstlane(mq.w)) >> jh;

            const double wa0 = (double)wa.x, wa1 = (double)wa.y,
                         wa2 = (double)wa.z, wa3 = (double)wa.w;
            const double wb0 = (double)wb.x, wb1 = (double)wb.y,
                         wb2 = (double)wb.z, wb3 = (double)wb.w;
#pragma unroll
            for (int j = 0; j < 8; ++j) {
                const double s0 = (double)((m0 >> j) & 1u);
                const double s1 = (double)((m1 >> j) & 1u);
                const double s2 = (double)((m2 >> j) & 1u);
                const double s3 = (double)((m3 >> j) & 1u);
                accA[j] += wa0 * s0 + wa1 * s1 + wa2 * s2 + wa3 * s3;
                accB[j] += wb0 * s0 + wb1 * s1 + wb2 * s2 + wb3 * s3;
            }
        }
    }

#pragma unroll
    for (int j = 0; j < 8; ++j) {
        const size_t base = ((size_t)blockIdx.y * BB + jh + j) * NN;
        partial[base + nA] = accA[j];
        partial[base + nA + HN] = accB[j];
    }
}

// ---------------- LIF update kernel ----------------
template <int G>
__global__ __launch_bounds__(256) void upd_kernel(
    const float* __restrict__ ext_exc,   // [T][BB][NE]
    const float* __restrict__ ext_inh,   // [T][BB][NI]
    const double* __restrict__ partial,  // [G][BB][NN]
    double* __restrict__ v,              // [BB][NN]
    float* __restrict__ out,             // [T][BB][NN]
    int t)
{
    const int idx = blockIdx.x * 256 + threadIdx.x;   // < BB*NN
    const int b = idx / NN;
    const int n = idx - b * NN;

    const float ext = (n < NE)
        ? ext_exc[((size_t)t * BB + b) * NE + n]
        : ext_inh[((size_t)t * BB + b) * NI + (n - NE)];

    double acc = (double)ext;
#pragma unroll
    for (int g = 0; g < G; ++g)
        acc += partial[((size_t)g * BB + b) * NN + n];

    const double vv = v[idx] * 0.9 + acc;
    const double sp = (vv > 1.0) ? 1.0 : 0.0;
    out[(size_t)t * BB * NN + idx] = (float)sp;
    v[idx] = vv * (1.0 - sp);
}

extern "C" void kernel_launch(void* const* d_in, const int* in_sizes, int n_in,
                              void* d_out, int out_size, void* d_ws, size_t ws_size,
                              hipStream_t stream) {
    const float* ext_exc = (const float*)d_in[0];
    const float* ext_inh = (const float*)d_in[1];
    const float* W_ee = (const float*)d_in[2];
    const float* W_ei = (const float*)d_in[3];
    const float* W_ie = (const float*)d_in[4];
    const float* W_ii = (const float*)d_in[5];
    float* out = (float*)d_out;

    const int T = in_sizes[0] / (BB * NE);   // 64

    const size_t SN = (size_t)BB * NN;       // 163840
    double* v = (double*)d_ws;               // [BB][NN] fp64
    u32* mask = (u32*)(v + SN);              // [NN]
    const size_t stateBytes = SN * 8 + (size_t)NN * 4;   // ~1.33 MB
    double* partial = (double*)((char*)d_ws + stateBytes);

    // k-split G: 16 preferred (21 MB partial), 8 fallback
    int G = 16;
    if (stateBytes + (size_t)G * SN * sizeof(double) > ws_size) G = 8;

    hipMemsetAsync(d_ws, 0, stateBytes, stream);   // v = 0, mask = 0

    for (int t = 0; t < T; ++t) {
        if (G == 16) {
            mv_kernel<320><<<dim3(HN / 64, 16), 256, 0, stream>>>(
                W_ee, W_ei, W_ie, W_ii, mask, partial);
            upd_kernel<16><<<(int)(SN / 256), 256, 0, stream>>>(
                ext_exc, ext_inh, partial, v, out, t);
        } else {
            mv_kernel<640><<<dim3(HN / 64, 8), 256, 0, stream>>>(
                W_ee, W_ei, W_ie, W_ii, mask, partial);
            upd_kernel<8><<<(int)(SN / 256), 256, 0, stream>>>(
                ext_exc, ext_inh, partial, v, out, t);
        }
        pack_kernel<<<NN / 256, 256, 0, stream>>>(out + (size_t)t * SN, mask);
    }
}